// Round 2
// baseline (919.927 us; speedup 1.0000x reference)
//
#include <hip/hip_runtime.h>
#include <cstddef>
#include <cstdint>

// Problem constants (fixed by reference setup_inputs)
constexpr int NN = 16, CC = 256, HH = 64, WW = 64, HW = 64 * 64; // 4096
constexpr size_t FSZ = (size_t)NN * CC * HW;                      // 16,777,216

__device__ __forceinline__ float sigmoidf_(float x) { return 1.f / (1.f + expf(-x)); }

// ---------------------------------------------------------------------------
// Tiled fp32 GEMM core: Y[o, hw] tile 64x64, K-tile 16, 256 threads, 4x4/thread
// X: [Cin, HW] (one batch), Wm: [Cout, Cin] row-major
// ---------------------------------------------------------------------------
__device__ __forceinline__ void gemm_tile_acc(const float* __restrict__ Xb,
                                              const float* __restrict__ Wm,
                                              int Cin, int hw0, int o0,
                                              float acc[4][4]) {
    __shared__ __align__(16) float sW[16][64];
    __shared__ __align__(16) float sX[16][64];
    const int tid = threadIdx.x;
    const int tx = tid & 15, ty = tid >> 4;
    for (int k0 = 0; k0 < Cin; k0 += 16) {
        // W tile: 64 (o) x 16 (c), stored transposed sW[c][o]
        {
            const int o_l = tid >> 2;
            const int c_l = (tid & 3) << 2;
            const float4 wv = *(const float4*)(Wm + (size_t)(o0 + o_l) * Cin + k0 + c_l);
            sW[c_l + 0][o_l] = wv.x;
            sW[c_l + 1][o_l] = wv.y;
            sW[c_l + 2][o_l] = wv.z;
            sW[c_l + 3][o_l] = wv.w;
        }
        // X tile: 16 (c) x 64 (hw), coalesced float4
        {
            const int cx = tid >> 4;
            const int hx = (tid & 15) << 2;
            *(float4*)&sX[cx][hx] = *(const float4*)(Xb + (size_t)(k0 + cx) * HW + hw0 + hx);
        }
        __syncthreads();
#pragma unroll
        for (int k = 0; k < 16; ++k) {
            const float4 a = *(const float4*)&sW[k][ty << 2];
            const float4 b = *(const float4*)&sX[k][tx << 2];
            acc[0][0] += a.x * b.x; acc[0][1] += a.x * b.y; acc[0][2] += a.x * b.z; acc[0][3] += a.x * b.w;
            acc[1][0] += a.y * b.x; acc[1][1] += a.y * b.y; acc[1][2] += a.y * b.z; acc[1][3] += a.y * b.w;
            acc[2][0] += a.z * b.x; acc[2][1] += a.z * b.y; acc[2][2] += a.z * b.z; acc[2][3] += a.z * b.w;
            acc[3][0] += a.w * b.x; acc[3][1] += a.w * b.y; acc[3][2] += a.w * b.z; acc[3][3] += a.w * b.w;
        }
        __syncthreads();
    }
}

// grid (HW/64, 256/64, N). Y[n,o,hw] = sum_c W[o,c] X[n,c,hw] + bias[o]
__global__ __launch_bounds__(256) void gemm_plain_kernel(const float* __restrict__ X,
                                                         const float* __restrict__ Wm,
                                                         const float* __restrict__ bias,
                                                         float* __restrict__ Y, int Cin) {
    const int hw0 = blockIdx.x * 64, o0 = blockIdx.y * 64, n = blockIdx.z;
    float acc[4][4] = {};
    gemm_tile_acc(X + (size_t)n * Cin * HW, Wm, Cin, hw0, o0, acc);
    const int tx = threadIdx.x & 15, ty = threadIdx.x >> 4;
#pragma unroll
    for (int i = 0; i < 4; ++i) {
        const int o = o0 + (ty << 2) + i;
        const float bi = bias[o];
        float4 v = make_float4(acc[i][0] + bi, acc[i][1] + bi, acc[i][2] + bi, acc[i][3] + bi);
        *(float4*)(Y + ((size_t)(n * CC + o)) * HW + hw0 + (tx << 2)) = v;
    }
}

// conv3 GEMM with fused final-combine epilogue:
// xL = (conv3(dw)+b3)*gate[n,o] + A + (s_pix*XG - mu_g)*isd_g*gamma[o] + beta[o] + XG*ca_sig[n,o]
__global__ __launch_bounds__(256) void gemm_final_kernel(
    const float* __restrict__ X, const float* __restrict__ Wm, const float* __restrict__ bias,
    const float* __restrict__ A, const float* __restrict__ XG, const float* __restrict__ s_pix,
    const float* __restrict__ gate, const float* __restrict__ ca_sig,
    const float* __restrict__ mu_g, const float* __restrict__ isd_g,
    const float* __restrict__ gamma, const float* __restrict__ beta,
    float* __restrict__ out) {
    const int hw0 = blockIdx.x * 64, o0 = blockIdx.y * 64, n = blockIdx.z;
    float acc[4][4] = {};
    gemm_tile_acc(X + (size_t)n * CC * HW, Wm, CC, hw0, o0, acc);
    const int tx = threadIdx.x & 15, ty = threadIdx.x >> 4;
#pragma unroll
    for (int i = 0; i < 4; ++i) {
        const int o = o0 + (ty << 2) + i;
        const float bi = bias[o];
        const float g = gate[n * CC + o];
        const float cs = ca_sig[n * CC + o];
        const float mu = mu_g[n * 16 + (o >> 4)];
        const float isd = isd_g[n * 16 + (o >> 4)];
        const float gm = gamma[o], bt = beta[o];
        const size_t row = ((size_t)(n * CC + o)) * HW + hw0 + (tx << 2);
        const int pix = n * HW + hw0 + (tx << 2);
        float4 v;
        float* vp = &v.x;
#pragma unroll
        for (int j = 0; j < 4; ++j) {
            const float t = acc[i][j] + bi;
            const float xg = XG[row + j];
            const float sp = s_pix[pix + j];
            const float gui = (sp * xg - mu) * isd * gm + bt;
            vp[j] = t * g + A[row + j] + gui + xg * cs;
        }
        *(float4*)(out + row) = v;
    }
}

// grid NC (4096): XG = g1+g2, per-(n,c) sum and sumsq
__global__ __launch_bounds__(256) void xg_stats_kernel(const float* __restrict__ g1,
                                                       const float* __restrict__ g2,
                                                       float* __restrict__ XG,
                                                       float* __restrict__ sum_c,
                                                       float* __restrict__ sq_c) {
    const size_t base = (size_t)blockIdx.x * HW;
    float s = 0.f, q = 0.f;
#pragma unroll 4
    for (int r = 0; r < 16; ++r) {
        const size_t i = base + threadIdx.x + r * 256;
        const float xg = g1[i] + g2[i];
        XG[i] = xg;
        s += xg;
        q += xg * xg;
    }
    __shared__ float sm[8];
    for (int off = 32; off; off >>= 1) { s += __shfl_down(s, off); q += __shfl_down(q, off); }
    const int w = threadIdx.x >> 6;
    if ((threadIdx.x & 63) == 0) { sm[w] = s; sm[4 + w] = q; }
    __syncthreads();
    if (threadIdx.x == 0) {
        sum_c[blockIdx.x] = sm[0] + sm[1] + sm[2] + sm[3];
        sq_c[blockIdx.x] = sm[4] + sm[5] + sm[6] + sm[7];
    }
}

// grid N (16): rw=sigmoid(mean), ca conv1d(k=5,pad2)+sigmoid, group mu / 1/(sd+1e-10) (ddof=1)
__global__ __launch_bounds__(256) void stats2_kernel(const float* __restrict__ sum_c,
                                                     const float* __restrict__ sq_c,
                                                     const float* __restrict__ caw,
                                                     float* __restrict__ rw,
                                                     float* __restrict__ ca_sig,
                                                     float* __restrict__ mu_g,
                                                     float* __restrict__ isd_g) {
    const int n = blockIdx.x, c = threadIdx.x;
    __shared__ float m[256];
    const float mean = sum_c[n * CC + c] * (1.f / (float)HW);
    m[c] = mean;
    rw[n * CC + c] = sigmoidf_(mean);
    __syncthreads();
    float y = 0.f;
#pragma unroll
    for (int k = 0; k < 5; ++k) {
        const int cc = c - 2 + k;
        if (cc >= 0 && cc < 256) y += m[cc] * caw[k];
    }
    ca_sig[n * CC + c] = sigmoidf_(y);
    if (c < 16) {
        float S = 0.f, Q = 0.f;
        for (int j = 0; j < 16; ++j) {
            S += sum_c[n * CC + c * 16 + j];
            Q += sq_c[n * CC + c * 16 + j];
        }
        const float cnt = 65536.f;
        const float mu = S / cnt;
        float var = (Q - S * S / cnt) * (1.f / (cnt - 1.f));
        var = fmaxf(var, 0.f);
        mu_g[n * 16 + c] = mu;
        isd_g[n * 16 + c] = 1.f / (sqrtf(var) + 1e-10f);
    }
}

// grid N*HW/256 (256): s_pix = sigmoid(conv4g(XG))
__global__ __launch_bounds__(256) void conv4g_kernel(const float* __restrict__ XG,
                                                     const float* __restrict__ cgw,
                                                     const float* __restrict__ cgb,
                                                     float* __restrict__ s_pix) {
    __shared__ float w[256];
    w[threadIdx.x] = cgw[threadIdx.x];
    __syncthreads();
    const int p = blockIdx.x * 256 + threadIdx.x;
    const int n = p >> 12, hw = p & 4095;
    const float* base = XG + (size_t)n * CC * HW + hw;
    float s = cgb[0];
#pragma unroll 8
    for (int c = 0; c < 256; ++c) s += base[(size_t)c * HW] * w[c];
    s_pix[p] = sigmoidf_(s);
}

// grid NC: split XG into x_up (-> out buf) / x_low (in-place over g1); sum x_low per (n,c)
__global__ __launch_bounds__(256) void masks_kernel(float* g1_xlow,  // aliased in/out, no restrict
                                                    const float* __restrict__ g2,
                                                    const float* __restrict__ XG,
                                                    const float* __restrict__ rw,
                                                    const float* __restrict__ bng,
                                                    const float* __restrict__ bnb,
                                                    const float* __restrict__ bnrm,
                                                    const float* __restrict__ bnrv,
                                                    float* __restrict__ xup,
                                                    float* __restrict__ xlow_sum) {
    const int nc = blockIdx.x;
    const int c = nc & 255;
    const float inv = bng[c] / sqrtf(bnrv[c] + 1e-5f);
    const float off = bnb[c] - bnrm[c] * inv;
    const float rwv = rw[nc];
    const size_t base = (size_t)nc * HW;
    float lsum = 0.f;
#pragma unroll 4
    for (int r = 0; r < 16; ++r) {
        const size_t i = base + threadIdx.x + r * 256;
        const float a = g1_xlow[i];
        const float b = g2[i];
        const float xg = XG[i];
        const float w1 = sigmoidf_(inv * a + off);
        const float w2 = sigmoidf_(inv * b + off);
        const float cu = (rwv >= w1 ? 1.f : 0.f) + (rwv >= w2 ? 1.f : 0.f);
        xup[i] = xg * cu;
        const float xl = xg * (2.f - cu);
        g1_xlow[i] = xl;
        lsum += xl;
    }
    __shared__ float sm[4];
    for (int off2 = 32; off2; off2 >>= 1) lsum += __shfl_down(lsum, off2);
    if ((threadIdx.x & 63) == 0) sm[threadIdx.x >> 6] = lsum;
    __syncthreads();
    if (threadIdx.x == 0) xlow_sum[nc] = sm[0] + sm[1] + sm[2] + sm[3];
}

// grid N: gate = softmax_c(relu(xlow_mean @ gate_w^T + gate_b))
__global__ __launch_bounds__(256) void gate_kernel(const float* __restrict__ xlow_sum,
                                                   const float* __restrict__ gatew,
                                                   const float* __restrict__ gateb,
                                                   float* __restrict__ gate) {
    const int n = blockIdx.x, c = threadIdx.x;
    __shared__ float xm[256];
    __shared__ float red[256];
    xm[c] = xlow_sum[n * CC + c] * (1.f / (float)HW);
    __syncthreads();
    float acc = gateb[c];
    const float* wr = gatew + (size_t)c * 256;
#pragma unroll 8
    for (int k = 0; k < 256; ++k) acc += xm[k] * wr[k];
    const float v = fmaxf(acc, 0.f);
    red[c] = v;
    __syncthreads();
    for (int s = 128; s > 0; s >>= 1) {
        if (c < s) red[c] = fmaxf(red[c], red[c + s]);
        __syncthreads();
    }
    const float mx = red[0];
    __syncthreads();
    const float e = expf(v - mx);
    red[c] = e;
    __syncthreads();
    for (int s = 128; s > 0; s >>= 1) {
        if (c < s) red[c] += red[c + s];
        __syncthreads();
    }
    gate[n * CC + c] = e / red[0];
}

// grid NC: depthwise 3x3 (pad 1) on x_low via LDS slab
__global__ __launch_bounds__(256) void dwconv_kernel(const float* __restrict__ xlow,
                                                     const float* __restrict__ dww,
                                                     const float* __restrict__ dwb,
                                                     float* __restrict__ out) {
    const int c = blockIdx.x & 255;
    __shared__ float sl[64][65];
    const size_t base = (size_t)blockIdx.x * HW;
    for (int r = 0; r < 16; ++r) {
        const int idx = threadIdx.x + r * 256;
        sl[idx >> 6][idx & 63] = xlow[base + idx];
    }
    float wk[9];
#pragma unroll
    for (int j = 0; j < 9; ++j) wk[j] = dww[c * 9 + j];
    const float bias = dwb[c];
    __syncthreads();
    for (int r = 0; r < 16; ++r) {
        const int idx = threadIdx.x + r * 256;
        const int h = idx >> 6, w = idx & 63;
        float acc = bias;
#pragma unroll
        for (int dh = 0; dh < 3; ++dh) {
            const int hh = h + dh - 1;
            if (hh < 0 || hh > 63) continue;
#pragma unroll
            for (int dw2 = 0; dw2 < 3; ++dw2) {
                const int ww2 = w + dw2 - 1;
                if (ww2 < 0 || ww2 > 63) continue;
                acc += sl[hh][ww2] * wk[dh * 3 + dw2];
            }
        }
        out[base + idx] = acc;
    }
}

// grid NC: xh[n,c,h]=mean_w xL, xw[n,c,w]=mean_h xL
__global__ __launch_bounds__(256) void pool_kernel(const float* __restrict__ xL,
                                                   float* __restrict__ xh,
                                                   float* __restrict__ xw) {
    __shared__ float sl[64][65];
    const size_t base = (size_t)blockIdx.x * HW;
    for (int r = 0; r < 16; ++r) {
        const int idx = threadIdx.x + r * 256;
        sl[idx >> 6][idx & 63] = xL[base + idx];
    }
    __syncthreads();
    const int t = threadIdx.x;
    if (t < 64) {
        float s = 0.f;
        for (int w = 0; w < 64; ++w) s += sl[t][w];
        xh[(size_t)blockIdx.x * 64 + t] = s * (1.f / 64.f);
    } else if (t < 128) {
        const int w = t - 64;
        float s = 0.f;
        for (int h = 0; h < 64; ++h) s += sl[h][w];
        xw[(size_t)blockIdx.x * 64 + w] = s * (1.f / 64.f);
    }
}

// grid N: yc = relu(bn(la1 @ [xh;xw])); sh = sig(fh@yc_h), sw = sig(fw@yc_w)
__global__ __launch_bounds__(256) void local_att_kernel(const float* __restrict__ xh,
                                                        const float* __restrict__ xw,
                                                        const float* __restrict__ la1w,
                                                        const float* __restrict__ lag,
                                                        const float* __restrict__ lab,
                                                        const float* __restrict__ larm,
                                                        const float* __restrict__ larv,
                                                        const float* __restrict__ fhw,
                                                        const float* __restrict__ fww,
                                                        float* __restrict__ sh,
                                                        float* __restrict__ sw) {
    const int n = blockIdx.x;
    __shared__ float w1s[16 * 256];
    __shared__ float fhs[256 * 16];
    __shared__ float fws[256 * 16];
    __shared__ float ycs[16][128];
    for (int i = threadIdx.x; i < 4096; i += 256) {
        w1s[i] = la1w[i];
        fhs[i] = fhw[i];
        fws[i] = fww[i];
    }
    __syncthreads();
    for (int idx = threadIdx.x; idx < 2048; idx += 256) {
        const int m = idx >> 7, p = idx & 127;
        const float* vsrc = (p < 64) ? (xh + (size_t)n * CC * 64 + p)
                                     : (xw + (size_t)n * CC * 64 + (p - 64));
        float acc = 0.f;
#pragma unroll 8
        for (int c = 0; c < 256; ++c) acc += w1s[m * 256 + c] * vsrc[(size_t)c * 64];
        const float inv = lag[m] / sqrtf(larv[m] + 1e-5f);
        const float off = lab[m] - larm[m] * inv;
        ycs[m][p] = fmaxf(inv * acc + off, 0.f);
    }
    __syncthreads();
    for (int idx = threadIdx.x; idx < 16384; idx += 256) {
        const int c = idx >> 6, h = idx & 63;
        float a1 = 0.f, a2 = 0.f;
#pragma unroll
        for (int m = 0; m < 16; ++m) {
            a1 += fhs[c * 16 + m] * ycs[m][h];
            a2 += fws[c * 16 + m] * ycs[m][64 + h];
        }
        sh[(size_t)n * CC * 64 + idx] = sigmoidf_(a1);
        sw[(size_t)n * CC * 64 + idx] = sigmoidf_(a2);
    }
}

// grid NC: out *= sh[h]*sw[w], in place
__global__ __launch_bounds__(256) void final_kernel(float* __restrict__ out,
                                                    const float* __restrict__ sh,
                                                    const float* __restrict__ sw) {
    __shared__ float shs[64], sws[64];
    const int t = threadIdx.x;
    if (t < 64) shs[t] = sh[(size_t)blockIdx.x * 64 + t];
    else if (t < 128) sws[t - 64] = sw[(size_t)blockIdx.x * 64 + (t - 64)];
    __syncthreads();
    const size_t base = (size_t)blockIdx.x * HW;
#pragma unroll 4
    for (int r = 0; r < 16; ++r) {
        const int idx = t + r * 256;
        out[base + idx] *= shs[idx >> 6] * sws[idx & 63];
    }
}

extern "C" void kernel_launch(void* const* d_in, const int* in_sizes, int n_in,
                              void* d_out, int out_size, void* d_ws, size_t ws_size,
                              hipStream_t stream) {
    const float* x1 = (const float*)d_in[0];
    const float* x2 = (const float*)d_in[1];
    const float* c1w = (const float*)d_in[2];
    const float* c1b = (const float*)d_in[3];
    const float* c2w = (const float*)d_in[4];
    const float* c2b = (const float*)d_in[5];
    const float* c3w = (const float*)d_in[6];
    const float* c3b = (const float*)d_in[7];
    const float* c4w = (const float*)d_in[8];
    const float* c4b = (const float*)d_in[9];
    const float* cgw = (const float*)d_in[10];
    const float* cgb = (const float*)d_in[11];
    const float* bng = (const float*)d_in[12];
    const float* bnb = (const float*)d_in[13];
    const float* bnrm = (const float*)d_in[14];
    const float* bnrv = (const float*)d_in[15];
    const float* gamma = (const float*)d_in[16];
    const float* beta = (const float*)d_in[17];
    const float* gatew = (const float*)d_in[18];
    const float* gateb = (const float*)d_in[19];
    const float* dww = (const float*)d_in[20];
    const float* dwb = (const float*)d_in[21];
    // d_in[22], d_in[23]: interact_w/b — dead code in reference (softmax over size-1 axis == 1)
    const float* caw = (const float*)d_in[24];
    const float* la1w = (const float*)d_in[25];
    const float* lag = (const float*)d_in[26];
    const float* lab = (const float*)d_in[27];
    const float* larm = (const float*)d_in[28];
    const float* larv = (const float*)d_in[29];
    const float* fhw = (const float*)d_in[30];
    const float* fww = (const float*)d_in[31];

    float* ws = (float*)d_ws;
    float* buf0 = ws;            // g1 -> x_low -> conv4 output A
    float* buf1 = ws + FSZ;      // g2 -> dw
    float* buf2 = ws + 2 * FSZ;  // XG
    float* sp = ws + 3 * FSZ;
    float* sum_c = sp;    sp += 4096;   // later reused as gate
    float* sq_c = sp;     sp += 4096;
    float* rw = sp;       sp += 4096;
    float* ca_sig = sp;   sp += 4096;
    float* xlow_sum = sp; sp += 4096;
    float* mu_g = sp;     sp += 256;
    float* isd_g = sp;    sp += 256;
    float* s_pix = sp;    sp += (size_t)NN * HW;       // 65536
    float* xh = sp;       sp += (size_t)NN * CC * 64;  // 262144
    float* xwb = sp;      sp += (size_t)NN * CC * 64;
    float* shb = sp;      sp += (size_t)NN * CC * 64;
    float* swb = sp;      sp += (size_t)NN * CC * 64;

    float* out = (float*)d_out;

    const dim3 gg(HW / 64, CC / 64, NN);  // (64, 4, 16)

    // 1-2: g1 = conv1(x1), g2 = conv2(x2)
    gemm_plain_kernel<<<gg, 256, 0, stream>>>(x1, c1w, c1b, buf0, CC);
    gemm_plain_kernel<<<gg, 256, 0, stream>>>(x2, c2w, c2b, buf1, CC);
    // 3: XG = g1+g2 + per-channel stats
    xg_stats_kernel<<<NN * CC, 256, 0, stream>>>(buf0, buf1, buf2, sum_c, sq_c);
    // 4: rw, channel-att sigmoid, group mu/invsd
    stats2_kernel<<<NN, 256, 0, stream>>>(sum_c, sq_c, caw, rw, ca_sig, mu_g, isd_g);
    // 5: s_pix = sigmoid(conv4g(XG))
    conv4g_kernel<<<NN * HW / 256, 256, 0, stream>>>(buf2, cgw, cgb, s_pix);
    // 6: masks -> x_up (d_out), x_low (in place over g1), x_low row sums
    masks_kernel<<<NN * CC, 256, 0, stream>>>(buf0, buf1, buf2, rw, bng, bnb, bnrm, bnrv,
                                              out, xlow_sum);
    // 7: gate softmax (output reuses sum_c — dead after stats2)
    float* gate = sum_c;
    gate_kernel<<<NN, 256, 0, stream>>>(xlow_sum, gatew, gateb, gate);
    // 8: dwconv on x_low -> buf1 (g2 dead)
    dwconv_kernel<<<NN * CC, 256, 0, stream>>>(buf0, dww, dwb, buf1);
    // 9: A = conv4(x_up) -> buf0 (x_low dead)
    gemm_plain_kernel<<<gg, 256, 0, stream>>>(out, c4w, c4b, buf0, CC);
    // 10: xL = conv3(dw)*gate + A + x_gui + temp -> d_out
    gemm_final_kernel<<<gg, 256, 0, stream>>>(buf1, c3w, c3b, buf0, buf2, s_pix,
                                              gate, ca_sig, mu_g, isd_g,
                                              gamma, beta, out);
    // 11: pools
    pool_kernel<<<NN * CC, 256, 0, stream>>>(out, xh, xwb);
    // 12: coordinate attention -> sh, sw
    local_att_kernel<<<NN, 256, 0, stream>>>(xh, xwb, la1w, lag, lab, larm, larv,
                                             fhw, fww, shb, swb);
    // 13: out *= sh*sw
    final_kernel<<<NN * CC, 256, 0, stream>>>(out, shb, swb);
}

// Round 4
// 782.556 us; speedup vs baseline: 1.1755x; 1.1755x over previous
//
#include <hip/hip_runtime.h>
#include <cstddef>
#include <cstdint>

// Problem constants (fixed by reference setup_inputs)
constexpr int NN = 16, CC = 256, HH = 64, WW = 64, HW = 64 * 64; // 4096
constexpr size_t FSZ = (size_t)NN * CC * HW;                      // 16,777,216

typedef short bf16x8 __attribute__((ext_vector_type(8)));
typedef float f32x4 __attribute__((ext_vector_type(4)));

__device__ __forceinline__ float sigmoidf_(float x) { return 1.f / (1.f + expf(-x)); }

__device__ __forceinline__ unsigned short bf16_rne(float f) {
    uint32_t u = __builtin_bit_cast(uint32_t, f);
    u += 0x7FFFu + ((u >> 16) & 1u);
    return (unsigned short)(u >> 16);
}
__device__ __forceinline__ float bf16_tof(unsigned short h) {
    uint32_t u = ((uint32_t)h) << 16;
    return __builtin_bit_cast(float, u);
}

// ---------------------------------------------------------------------------
// Weight split: conv1/conv2 -> 3-way bf16 split, conv4 -> 2-way, conv3 -> bf16
// ---------------------------------------------------------------------------
__global__ __launch_bounds__(256) void wsplit_kernel(
    const float* __restrict__ w1, const float* __restrict__ w2,
    const float* __restrict__ w3, const float* __restrict__ w4,
    unsigned short* __restrict__ w1h, unsigned short* __restrict__ w1m, unsigned short* __restrict__ w1l,
    unsigned short* __restrict__ w2h, unsigned short* __restrict__ w2m, unsigned short* __restrict__ w2l,
    unsigned short* __restrict__ w4h, unsigned short* __restrict__ w4l,
    unsigned short* __restrict__ w3b) {
    const int i = blockIdx.x * 256 + threadIdx.x;  // 65536 weights each
    {
        float x = w1[i];
        unsigned short h = bf16_rne(x); float r = x - bf16_tof(h);
        unsigned short m = bf16_rne(r); float r2 = r - bf16_tof(m);
        w1h[i] = h; w1m[i] = m; w1l[i] = bf16_rne(r2);
    }
    {
        float x = w2[i];
        unsigned short h = bf16_rne(x); float r = x - bf16_tof(h);
        unsigned short m = bf16_rne(r); float r2 = r - bf16_tof(m);
        w2h[i] = h; w2m[i] = m; w2l[i] = bf16_rne(r2);
    }
    {
        float x = w4[i];
        unsigned short h = bf16_rne(x); float r = x - bf16_tof(h);
        w4h[i] = h; w4l[i] = bf16_rne(r);
    }
    w3b[i] = bf16_rne(w3[i]);
}

// ---------------------------------------------------------------------------
// Transpose + split: X fp32 [n][C][HW] -> NS bf16 arrays [n][HW][C]
// grid (HW/64, C/64, N), 256 threads
// ---------------------------------------------------------------------------
template <int NS>
__global__ __launch_bounds__(256) void tsplit_kernel(const float* __restrict__ X,
                                                     unsigned short* __restrict__ O0,
                                                     unsigned short* __restrict__ O1,
                                                     unsigned short* __restrict__ O2) {
    const int hw0 = blockIdx.x * 64, c0 = blockIdx.y * 64, n = blockIdx.z;
    __shared__ float sT[64][65];
    const int tid = threadIdx.x;
    {
        const int hwl = (tid & 15) << 2;
        const int cl = tid >> 4;  // 0..15
#pragma unroll
        for (int p = 0; p < 4; ++p) {
            const int c = cl + p * 16;
            const float4 v = *(const float4*)(X + ((size_t)(n * CC + c0 + c)) * HW + hw0 + hwl);
            sT[c][hwl] = v.x; sT[c][hwl + 1] = v.y; sT[c][hwl + 2] = v.z; sT[c][hwl + 3] = v.w;
        }
    }
    __syncthreads();
    const int hwl = tid >> 2, cb = (tid & 3) << 4;
    unsigned short h[16], m[16], l[16];
#pragma unroll
    for (int j = 0; j < 16; ++j) {
        const float x = sT[cb + j][hwl];
        const unsigned short hh = bf16_rne(x);
        h[j] = hh;
        if (NS >= 2) {
            const float r = x - bf16_tof(hh);
            const unsigned short mm = bf16_rne(r);
            m[j] = mm;
            if (NS >= 3) l[j] = bf16_rne(r - bf16_tof(mm));
        }
    }
    const size_t ob = ((size_t)(n * HW + hw0 + hwl)) * 256 + c0 + cb;
    *(int4*)(O0 + ob) = *(int4*)&h[0]; *(int4*)(O0 + ob + 8) = *(int4*)&h[8];
    if (NS >= 2) { *(int4*)(O1 + ob) = *(int4*)&m[0]; *(int4*)(O1 + ob + 8) = *(int4*)&m[8]; }
    if (NS >= 3) { *(int4*)(O2 + ob) = *(int4*)&l[0]; *(int4*)(O2 + ob + 8) = *(int4*)&l[8]; }
}

// ---------------------------------------------------------------------------
// MFMA GEMM core: Y-tile 64(o) x 64(hw), K=256 in steps of 32, 4 waves.
// XT: [n][HW][256] bf16 splits (k-contiguous); WS: [256][256] bf16 splits.
// NS=3 -> 6 products (~fp32), NS=2 -> 3, NS=1 -> 1.
// Wave w handles o-rows [w*16, w*16+16), all 64 hw (4 n-tiles of 16).
// acc tile D: row(o) = quad*4+reg, col(hw) = lane&15 (verified gfx950 C/D layout).
// ---------------------------------------------------------------------------
template <int NS>
__device__ __forceinline__ void mfma_core(const unsigned short* X0,
                                          const unsigned short* X1,
                                          const unsigned short* X2,
                                          const unsigned short* W0,
                                          const unsigned short* W1,
                                          const unsigned short* W2,
                                          int n, int hw0, int o0, f32x4 acc[4]) {
    __shared__ unsigned short sX[NS][64][40];  // pitch 40 bf16 = 80 B
    __shared__ unsigned short sW[NS][64][40];
    const int tid = threadIdx.x;
    const int row = tid >> 2, koff = (tid & 3) << 3;
    const int lane = tid & 63, wv = tid >> 6, quad = lane >> 4, nlo = lane & 15;
    const unsigned short* Xs[3] = {X0, X1, X2};
    const unsigned short* Ws[3] = {W0, W1, W2};
    const size_t xbase = ((size_t)(n * HW + hw0 + row)) * 256 + koff;
    const size_t wbase = ((size_t)(o0 + row)) * 256 + koff;
    for (int k0 = 0; k0 < 256; k0 += 32) {
#pragma unroll
        for (int s = 0; s < NS; ++s) {
            *(int4*)&sX[s][row][koff] = *(const int4*)(Xs[s] + xbase + k0);
            *(int4*)&sW[s][row][koff] = *(const int4*)(Ws[s] + wbase + k0);
        }
        __syncthreads();
        bf16x8 af[NS];
#pragma unroll
        for (int s = 0; s < NS; ++s) af[s] = *(const bf16x8*)&sW[s][wv * 16 + nlo][quad * 8];
#pragma unroll
        for (int nt = 0; nt < 4; ++nt) {
            bf16x8 bfr[NS];
#pragma unroll
            for (int s = 0; s < NS; ++s) bfr[s] = *(const bf16x8*)&sX[s][nt * 16 + nlo][quad * 8];
            // accumulate smallest-magnitude products first
            if (NS == 3) {
                acc[nt] = __builtin_amdgcn_mfma_f32_16x16x32_bf16(af[1], bfr[1], acc[nt], 0, 0, 0);
                acc[nt] = __builtin_amdgcn_mfma_f32_16x16x32_bf16(af[0], bfr[2], acc[nt], 0, 0, 0);
                acc[nt] = __builtin_amdgcn_mfma_f32_16x16x32_bf16(af[2], bfr[0], acc[nt], 0, 0, 0);
                acc[nt] = __builtin_amdgcn_mfma_f32_16x16x32_bf16(af[0], bfr[1], acc[nt], 0, 0, 0);
                acc[nt] = __builtin_amdgcn_mfma_f32_16x16x32_bf16(af[1], bfr[0], acc[nt], 0, 0, 0);
                acc[nt] = __builtin_amdgcn_mfma_f32_16x16x32_bf16(af[0], bfr[0], acc[nt], 0, 0, 0);
            } else if (NS == 2) {
                acc[nt] = __builtin_amdgcn_mfma_f32_16x16x32_bf16(af[0], bfr[1], acc[nt], 0, 0, 0);
                acc[nt] = __builtin_amdgcn_mfma_f32_16x16x32_bf16(af[1], bfr[0], acc[nt], 0, 0, 0);
                acc[nt] = __builtin_amdgcn_mfma_f32_16x16x32_bf16(af[0], bfr[0], acc[nt], 0, 0, 0);
            } else {
                acc[nt] = __builtin_amdgcn_mfma_f32_16x16x32_bf16(af[0], bfr[0], acc[nt], 0, 0, 0);
            }
        }
        __syncthreads();
    }
}

template <int NS>
__global__ __launch_bounds__(256) void gemm_mfma_kernel(
    const unsigned short* __restrict__ X0, const unsigned short* __restrict__ X1,
    const unsigned short* __restrict__ X2, const unsigned short* __restrict__ W0,
    const unsigned short* __restrict__ W1, const unsigned short* __restrict__ W2,
    const float* __restrict__ bias, float* __restrict__ Y) {
    const int hw0 = blockIdx.x * 64, o0 = blockIdx.y * 64, n = blockIdx.z;
    f32x4 acc[4] = {};
    mfma_core<NS>(X0, X1, X2, W0, W1, W2, n, hw0, o0, acc);
    const int lane = threadIdx.x & 63, wv = threadIdx.x >> 6;
    const int quad = lane >> 4, nlo = lane & 15;
    const int om = o0 + wv * 16 + quad * 4;
#pragma unroll
    for (int nt = 0; nt < 4; ++nt) {
        const int hw = hw0 + nt * 16 + nlo;
#pragma unroll
        for (int r = 0; r < 4; ++r) {
            const int o = om + r;
            Y[((size_t)(n * CC + o)) * HW + hw] = acc[nt][r] + bias[o];
        }
    }
}

// conv3 GEMM (plain bf16) with fused final-combine epilogue:
// xL = (conv3(dw)+b3)*gate[n,o] + A + (s_pix*XG - mu_g)*isd_g*gamma[o] + beta[o] + XG*ca_sig[n,o]
// NOTE: A and out may ALIAS (in-place: same thread reads A[i] then writes out[i]) — no restrict.
__global__ __launch_bounds__(256) void gemm_final_kernel(
    const unsigned short* __restrict__ X0, const unsigned short* __restrict__ W0,
    const float* __restrict__ bias,
    const float* A, const float* __restrict__ XG, const float* __restrict__ s_pix,
    const float* __restrict__ gate, const float* __restrict__ ca_sig,
    const float* __restrict__ mu_g, const float* __restrict__ isd_g,
    const float* __restrict__ gamma, const float* __restrict__ beta,
    float* out) {
    const int hw0 = blockIdx.x * 64, o0 = blockIdx.y * 64, n = blockIdx.z;
    f32x4 acc[4] = {};
    mfma_core<1>(X0, nullptr, nullptr, W0, nullptr, nullptr, n, hw0, o0, acc);
    const int lane = threadIdx.x & 63, wv = threadIdx.x >> 6;
    const int quad = lane >> 4, nlo = lane & 15;
    const int om = o0 + wv * 16 + quad * 4;
#pragma unroll
    for (int nt = 0; nt < 4; ++nt) {
        const int hw = hw0 + nt * 16 + nlo;
        const int pix = n * HW + hw;
        const float sp = s_pix[pix];
#pragma unroll
        for (int r = 0; r < 4; ++r) {
            const int o = om + r;
            const float g = gate[n * CC + o];
            const float cs = ca_sig[n * CC + o];
            const float mu = mu_g[n * 16 + (o >> 4)];
            const float isd = isd_g[n * 16 + (o >> 4)];
            const size_t rowi = ((size_t)(n * CC + o)) * HW + hw;
            const float xg = XG[rowi];
            const float gui = (sp * xg - mu) * isd * gamma[o] + beta[o];
            out[rowi] = (acc[nt][r] + bias[o]) * g + A[rowi] + gui + xg * cs;
        }
    }
}

// grid NC (4096): XG = g1+g2, per-(n,c) sum and sumsq
__global__ __launch_bounds__(256) void xg_stats_kernel(const float* __restrict__ g1,
                                                       const float* __restrict__ g2,
                                                       float* __restrict__ XG,
                                                       float* __restrict__ sum_c,
                                                       float* __restrict__ sq_c) {
    const size_t base = (size_t)blockIdx.x * HW;
    float s = 0.f, q = 0.f;
#pragma unroll 4
    for (int r = 0; r < 16; ++r) {
        const size_t i = base + threadIdx.x + r * 256;
        const float xg = g1[i] + g2[i];
        XG[i] = xg;
        s += xg;
        q += xg * xg;
    }
    __shared__ float sm[8];
    for (int off = 32; off; off >>= 1) { s += __shfl_down(s, off); q += __shfl_down(q, off); }
    const int w = threadIdx.x >> 6;
    if ((threadIdx.x & 63) == 0) { sm[w] = s; sm[4 + w] = q; }
    __syncthreads();
    if (threadIdx.x == 0) {
        sum_c[blockIdx.x] = sm[0] + sm[1] + sm[2] + sm[3];
        sq_c[blockIdx.x] = sm[4] + sm[5] + sm[6] + sm[7];
    }
}

// grid N (16): rw=sigmoid(mean), ca conv1d(k=5,pad2)+sigmoid, group mu / 1/(sd+1e-10)
__global__ __launch_bounds__(256) void stats2_kernel(const float* __restrict__ sum_c,
                                                     const float* __restrict__ sq_c,
                                                     const float* __restrict__ caw,
                                                     float* __restrict__ rw,
                                                     float* __restrict__ ca_sig,
                                                     float* __restrict__ mu_g,
                                                     float* __restrict__ isd_g) {
    const int n = blockIdx.x, c = threadIdx.x;
    __shared__ float m[256];
    const float mean = sum_c[n * CC + c] * (1.f / (float)HW);
    m[c] = mean;
    rw[n * CC + c] = sigmoidf_(mean);
    __syncthreads();
    float y = 0.f;
#pragma unroll
    for (int k = 0; k < 5; ++k) {
        const int cc = c - 2 + k;
        if (cc >= 0 && cc < 256) y += m[cc] * caw[k];
    }
    ca_sig[n * CC + c] = sigmoidf_(y);
    if (c < 16) {
        float S = 0.f, Q = 0.f;
        for (int j = 0; j < 16; ++j) {
            S += sum_c[n * CC + c * 16 + j];
            Q += sq_c[n * CC + c * 16 + j];
        }
        const float cnt = 65536.f;
        const float mu = S / cnt;
        float var = (Q - S * S / cnt) * (1.f / (cnt - 1.f));
        var = fmaxf(var, 0.f);
        mu_g[n * 16 + c] = mu;
        isd_g[n * 16 + c] = 1.f / (sqrtf(var) + 1e-10f);
    }
}

// grid N*HW/256 (256): s_pix = sigmoid(conv4g(XG))
__global__ __launch_bounds__(256) void conv4g_kernel(const float* __restrict__ XG,
                                                     const float* __restrict__ cgw,
                                                     const float* __restrict__ cgb,
                                                     float* __restrict__ s_pix) {
    __shared__ float w[256];
    w[threadIdx.x] = cgw[threadIdx.x];
    __syncthreads();
    const int p = blockIdx.x * 256 + threadIdx.x;
    const int n = p >> 12, hw = p & 4095;
    const float* base = XG + (size_t)n * CC * HW + hw;
    float s = cgb[0];
#pragma unroll 8
    for (int c = 0; c < 256; ++c) s += base[(size_t)c * HW] * w[c];
    s_pix[p] = sigmoidf_(s);
}

// grid NC: split XG into x_up / x_low (in-place over g1); sum x_low per (n,c)
__global__ __launch_bounds__(256) void masks_kernel(float* g1_xlow,  // aliased in/out
                                                    const float* __restrict__ g2,
                                                    const float* __restrict__ XG,
                                                    const float* __restrict__ rw,
                                                    const float* __restrict__ bng,
                                                    const float* __restrict__ bnb,
                                                    const float* __restrict__ bnrm,
                                                    const float* __restrict__ bnrv,
                                                    float* __restrict__ xup,
                                                    float* __restrict__ xlow_sum) {
    const int nc = blockIdx.x;
    const int c = nc & 255;
    const float inv = bng[c] / sqrtf(bnrv[c] + 1e-5f);
    const float off = bnb[c] - bnrm[c] * inv;
    const float rwv = rw[nc];
    const size_t base = (size_t)nc * HW;
    float lsum = 0.f;
#pragma unroll 4
    for (int r = 0; r < 16; ++r) {
        const size_t i = base + threadIdx.x + r * 256;
        const float a = g1_xlow[i];
        const float b = g2[i];
        const float xg = XG[i];
        const float w1 = sigmoidf_(inv * a + off);
        const float w2 = sigmoidf_(inv * b + off);
        const float cu = (rwv >= w1 ? 1.f : 0.f) + (rwv >= w2 ? 1.f : 0.f);
        xup[i] = xg * cu;
        const float xl = xg * (2.f - cu);
        g1_xlow[i] = xl;
        lsum += xl;
    }
    __shared__ float sm[4];
    for (int off2 = 32; off2; off2 >>= 1) lsum += __shfl_down(lsum, off2);
    if ((threadIdx.x & 63) == 0) sm[threadIdx.x >> 6] = lsum;
    __syncthreads();
    if (threadIdx.x == 0) xlow_sum[nc] = sm[0] + sm[1] + sm[2] + sm[3];
}

// grid N: gate = softmax_c(relu(xlow_mean @ gate_w^T + gate_b))
__global__ __launch_bounds__(256) void gate_kernel(const float* __restrict__ xlow_sum,
                                                   const float* __restrict__ gatew,
                                                   const float* __restrict__ gateb,
                                                   float* __restrict__ gate) {
    const int n = blockIdx.x, c = threadIdx.x;
    __shared__ float xm[256];
    __shared__ float red[256];
    xm[c] = xlow_sum[n * CC + c] * (1.f / (float)HW);
    __syncthreads();
    float acc = gateb[c];
    const float* wr = gatew + (size_t)c * 256;
#pragma unroll 8
    for (int k = 0; k < 256; ++k) acc += xm[k] * wr[k];
    const float v = fmaxf(acc, 0.f);
    red[c] = v;
    __syncthreads();
    for (int s = 128; s > 0; s >>= 1) {
        if (c < s) red[c] = fmaxf(red[c], red[c + s]);
        __syncthreads();
    }
    const float mx = red[0];
    __syncthreads();
    const float e = expf(v - mx);
    red[c] = e;
    __syncthreads();
    for (int s = 128; s > 0; s >>= 1) {
        if (c < s) red[c] += red[c + s];
        __syncthreads();
    }
    gate[n * CC + c] = e / red[0];
}

// grid NC: depthwise 3x3 (pad 1) on x_low via LDS slab
__global__ __launch_bounds__(256) void dwconv_kernel(const float* __restrict__ xlow,
                                                     const float* __restrict__ dww,
                                                     const float* __restrict__ dwb,
                                                     float* __restrict__ out) {
    const int c = blockIdx.x & 255;
    __shared__ float sl[64][65];
    const size_t base = (size_t)blockIdx.x * HW;
    for (int r = 0; r < 16; ++r) {
        const int idx = threadIdx.x + r * 256;
        sl[idx >> 6][idx & 63] = xlow[base + idx];
    }
    float wk[9];
#pragma unroll
    for (int j = 0; j < 9; ++j) wk[j] = dww[c * 9 + j];
    const float bias = dwb[c];
    __syncthreads();
    for (int r = 0; r < 16; ++r) {
        const int idx = threadIdx.x + r * 256;
        const int h = idx >> 6, w = idx & 63;
        float acc = bias;
#pragma unroll
        for (int dh = 0; dh < 3; ++dh) {
            const int hh = h + dh - 1;
            if (hh < 0 || hh > 63) continue;
#pragma unroll
            for (int dw2 = 0; dw2 < 3; ++dw2) {
                const int ww2 = w + dw2 - 1;
                if (ww2 < 0 || ww2 > 63) continue;
                acc += sl[hh][ww2] * wk[dh * 3 + dw2];
            }
        }
        out[base + idx] = acc;
    }
}

// grid NC: xh[n,c,h]=mean_w xL, xw[n,c,w]=mean_h xL
__global__ __launch_bounds__(256) void pool_kernel(const float* __restrict__ xL,
                                                   float* __restrict__ xh,
                                                   float* __restrict__ xw) {
    __shared__ float sl[64][65];
    const size_t base = (size_t)blockIdx.x * HW;
    for (int r = 0; r < 16; ++r) {
        const int idx = threadIdx.x + r * 256;
        sl[idx >> 6][idx & 63] = xL[base + idx];
    }
    __syncthreads();
    const int t = threadIdx.x;
    if (t < 64) {
        float s = 0.f;
        for (int w = 0; w < 64; ++w) s += sl[t][w];
        xh[(size_t)blockIdx.x * 64 + t] = s * (1.f / 64.f);
    } else if (t < 128) {
        const int w = t - 64;
        float s = 0.f;
        for (int h = 0; h < 64; ++h) s += sl[h][w];
        xw[(size_t)blockIdx.x * 64 + w] = s * (1.f / 64.f);
    }
}

// grid N: yc = relu(bn(la1 @ [xh;xw])); sh = sig(fh@yc_h), sw = sig(fw@yc_w)
__global__ __launch_bounds__(256) void local_att_kernel(const float* __restrict__ xh,
                                                        const float* __restrict__ xw,
                                                        const float* __restrict__ la1w,
                                                        const float* __restrict__ lag,
                                                        const float* __restrict__ lab,
                                                        const float* __restrict__ larm,
                                                        const float* __restrict__ larv,
                                                        const float* __restrict__ fhw,
                                                        const float* __restrict__ fww,
                                                        float* __restrict__ sh,
                                                        float* __restrict__ sw) {
    const int n = blockIdx.x;
    __shared__ float w1s[16 * 256];
    __shared__ float fhs[256 * 16];
    __shared__ float fws[256 * 16];
    __shared__ float ycs[16][128];
    for (int i = threadIdx.x; i < 4096; i += 256) {
        w1s[i] = la1w[i];
        fhs[i] = fhw[i];
        fws[i] = fww[i];
    }
    __syncthreads();
    for (int idx = threadIdx.x; idx < 2048; idx += 256) {
        const int m = idx >> 7, p = idx & 127;
        const float* vsrc = (p < 64) ? (xh + (size_t)n * CC * 64 + p)
                                     : (xw + (size_t)n * CC * 64 + (p - 64));
        float acc = 0.f;
#pragma unroll 8
        for (int c = 0; c < 256; ++c) acc += w1s[m * 256 + c] * vsrc[(size_t)c * 64];
        const float inv = lag[m] / sqrtf(larv[m] + 1e-5f);
        const float off = lab[m] - larm[m] * inv;
        ycs[m][p] = fmaxf(inv * acc + off, 0.f);
    }
    __syncthreads();
    for (int idx = threadIdx.x; idx < 16384; idx += 256) {
        const int c = idx >> 6, h = idx & 63;
        float a1 = 0.f, a2 = 0.f;
#pragma unroll
        for (int m = 0; m < 16; ++m) {
            a1 += fhs[c * 16 + m] * ycs[m][h];
            a2 += fws[c * 16 + m] * ycs[m][64 + h];
        }
        sh[(size_t)n * CC * 64 + idx] = sigmoidf_(a1);
        sw[(size_t)n * CC * 64 + idx] = sigmoidf_(a2);
    }
}

// grid NC: out *= sh[h]*sw[w], in place
__global__ __launch_bounds__(256) void final_kernel(float* __restrict__ out,
                                                    const float* __restrict__ sh,
                                                    const float* __restrict__ sw) {
    __shared__ float shs[64], sws[64];
    const int t = threadIdx.x;
    if (t < 64) shs[t] = sh[(size_t)blockIdx.x * 64 + t];
    else if (t < 128) sws[t - 64] = sw[(size_t)blockIdx.x * 64 + (t - 64)];
    __syncthreads();
    const size_t base = (size_t)blockIdx.x * HW;
#pragma unroll 4
    for (int r = 0; r < 16; ++r) {
        const int idx = t + r * 256;
        out[base + idx] *= shs[idx >> 6] * sws[idx & 63];
    }
}

extern "C" void kernel_launch(void* const* d_in, const int* in_sizes, int n_in,
                              void* d_out, int out_size, void* d_ws, size_t ws_size,
                              hipStream_t stream) {
    const float* x1 = (const float*)d_in[0];
    const float* x2 = (const float*)d_in[1];
    const float* c1w = (const float*)d_in[2];
    const float* c1b = (const float*)d_in[3];
    const float* c2w = (const float*)d_in[4];
    const float* c2b = (const float*)d_in[5];
    const float* c3w = (const float*)d_in[6];
    const float* c3b = (const float*)d_in[7];
    const float* c4w = (const float*)d_in[8];
    const float* c4b = (const float*)d_in[9];
    const float* cgw = (const float*)d_in[10];
    const float* cgb = (const float*)d_in[11];
    const float* bng = (const float*)d_in[12];
    const float* bnb = (const float*)d_in[13];
    const float* bnrm = (const float*)d_in[14];
    const float* bnrv = (const float*)d_in[15];
    const float* gamma = (const float*)d_in[16];
    const float* beta = (const float*)d_in[17];
    const float* gatew = (const float*)d_in[18];
    const float* gateb = (const float*)d_in[19];
    const float* dww = (const float*)d_in[20];
    const float* dwb = (const float*)d_in[21];
    // d_in[22], d_in[23]: interact_w/b — dead code (softmax over size-1 axis == 1)
    const float* caw = (const float*)d_in[24];
    const float* la1w = (const float*)d_in[25];
    const float* lag = (const float*)d_in[26];
    const float* lab = (const float*)d_in[27];
    const float* larm = (const float*)d_in[28];
    const float* larv = (const float*)d_in[29];
    const float* fhw = (const float*)d_in[30];
    const float* fww = (const float*)d_in[31];

    // ---- Workspace plan (fits in R2's proven 206 MB footprint) ----
    // buf0: [conv1 out g1] -> x_low -> [conv4 splits (2 FSZ us)] -> [conv3 split]
    // buf1: [conv1 splits hi,mid (2 FSZ us)] -> g2 -> dw
    // buf2: [conv1 split lo / conv2 split lo (1 FSZ us, first half)] -> XG
    // d_out: [conv2 splits hi,mid (2 FSZ us)] -> x_up -> A -> final out
    float* ws = (float*)d_ws;
    float* buf0 = ws;
    float* buf1 = ws + FSZ;
    float* buf2 = ws + 2 * FSZ;
    float* sp = ws + 3 * FSZ;
    float* sum_c = sp;    sp += 4096;   // later reused as gate
    float* sq_c = sp;     sp += 4096;
    float* rw = sp;       sp += 4096;
    float* ca_sig = sp;   sp += 4096;
    float* xlow_sum = sp; sp += 4096;
    float* mu_g = sp;     sp += 256;
    float* isd_g = sp;    sp += 256;
    float* s_pix = sp;    sp += (size_t)NN * HW;       // 65536
    float* xh = sp;       sp += (size_t)NN * CC * 64;  // 262144
    float* xwb = sp;      sp += (size_t)NN * CC * 64;
    float* shb = sp;      sp += (size_t)NN * CC * 64;
    float* swb = sp;      sp += (size_t)NN * CC * 64;
    // weight splits overlap shb/swb (written only at step 12; weights dead by then)
    unsigned short* wsp = (unsigned short*)shb;
    unsigned short* w1h = wsp + 0 * 65536;
    unsigned short* w1m = wsp + 1 * 65536;
    unsigned short* w1l = wsp + 2 * 65536;
    unsigned short* w2h = wsp + 3 * 65536;
    unsigned short* w2m = wsp + 4 * 65536;
    unsigned short* w2l = wsp + 5 * 65536;
    unsigned short* w4h = wsp + 6 * 65536;
    unsigned short* w4l = wsp + 7 * 65536;
    unsigned short* w3b = wsp + 8 * 65536;

    float* out = (float*)d_out;

    const dim3 gg(HW / 64, CC / 64, NN);  // (64, 4, 16)

    // 0: weight splits
    wsplit_kernel<<<256, 256, 0, stream>>>(c1w, c2w, c3w, c4w, w1h, w1m, w1l,
                                           w2h, w2m, w2l, w4h, w4l, w3b);
    // 1: g1 = conv1(x1)  (3-split ~fp32 MFMA). Splits live in buf1 (hi,mid) + buf2 (lo).
    {
        unsigned short* sx0 = (unsigned short*)buf1;
        unsigned short* sx1 = (unsigned short*)buf1 + FSZ;
        unsigned short* sx2 = (unsigned short*)buf2;
        tsplit_kernel<3><<<gg, 256, 0, stream>>>(x1, sx0, sx1, sx2);
        gemm_mfma_kernel<3><<<gg, 256, 0, stream>>>(sx0, sx1, sx2, w1h, w1m, w1l, c1b, buf0);
    }
    // 2: g2 = conv2(x2). Splits live in d_out (hi,mid) + buf2 (lo). g2 -> buf1 (conv1 splits dead).
    {
        unsigned short* sx0 = (unsigned short*)out;
        unsigned short* sx1 = (unsigned short*)out + FSZ;
        unsigned short* sx2 = (unsigned short*)buf2;
        tsplit_kernel<3><<<gg, 256, 0, stream>>>(x2, sx0, sx1, sx2);
        gemm_mfma_kernel<3><<<gg, 256, 0, stream>>>(sx0, sx1, sx2, w2h, w2m, w2l, c2b, buf1);
    }
    // 3: XG = g1+g2 -> buf2 (conv2 lo-split dead) + per-channel stats
    xg_stats_kernel<<<NN * CC, 256, 0, stream>>>(buf0, buf1, buf2, sum_c, sq_c);
    // 4: rw, channel-att sigmoid, group mu/invsd
    stats2_kernel<<<NN, 256, 0, stream>>>(sum_c, sq_c, caw, rw, ca_sig, mu_g, isd_g);
    // 5: s_pix = sigmoid(conv4g(XG))
    conv4g_kernel<<<NN * HW / 256, 256, 0, stream>>>(buf2, cgw, cgb, s_pix);
    // 6: masks -> x_up (d_out; conv2 splits dead), x_low (in place over g1), x_low row sums
    masks_kernel<<<NN * CC, 256, 0, stream>>>(buf0, buf1, buf2, rw, bng, bnb, bnrm, bnrv,
                                              out, xlow_sum);
    // 7: gate softmax (output reuses sum_c)
    float* gate = sum_c;
    gate_kernel<<<NN, 256, 0, stream>>>(xlow_sum, gatew, gateb, gate);
    // 8: dwconv on x_low -> buf1 (g2 dead)
    dwconv_kernel<<<NN * CC, 256, 0, stream>>>(buf0, dww, dwb, buf1);
    // 9: A = conv4(x_up) (2-split MFMA). Splits -> buf0 (x_low dead). A -> d_out (over x_up).
    {
        unsigned short* sx0 = (unsigned short*)buf0;
        unsigned short* sx1 = (unsigned short*)buf0 + FSZ;
        tsplit_kernel<2><<<gg, 256, 0, stream>>>(out, sx0, sx1, nullptr);
        gemm_mfma_kernel<2><<<gg, 256, 0, stream>>>(sx0, sx1, nullptr, w4h, w4l, nullptr,
                                                    c4b, out);
    }
    // 10: xL = conv3(dw)*gate + A + x_gui + temp -> d_out IN PLACE (A aliases out).
    //     conv3 split -> buf0 (conv4 splits dead after gemm above).
    {
        unsigned short* sx0 = (unsigned short*)buf0;
        tsplit_kernel<1><<<gg, 256, 0, stream>>>(buf1, sx0, nullptr, nullptr);
        gemm_final_kernel<<<gg, 256, 0, stream>>>(sx0, w3b, c3b, out, buf2, s_pix,
                                                  gate, ca_sig, mu_g, isd_g, gamma, beta, out);
    }
    // 11: pools
    pool_kernel<<<NN * CC, 256, 0, stream>>>(out, xh, xwb);
    // 12: coordinate attention -> sh, sw (overwrites weight-split region — weights dead)
    local_att_kernel<<<NN, 256, 0, stream>>>(xh, xwb, la1w, lag, lab, larm, larv,
                                             fhw, fww, shb, swb);
    // 13: out *= sh*sw
    final_kernel<<<NN * CC, 256, 0, stream>>>(out, shb, swb);
}

// Round 5
// 729.368 us; speedup vs baseline: 1.2613x; 1.0729x over previous
//
#include <hip/hip_runtime.h>
#include <cstddef>
#include <cstdint>

// Problem constants (fixed by reference setup_inputs)
constexpr int NN = 16, CC = 256, HH = 64, WW = 64, HW = 64 * 64; // 4096
constexpr size_t FSZ = (size_t)NN * CC * HW;                      // 16,777,216

typedef short bf16x8 __attribute__((ext_vector_type(8)));
typedef float f32x4 __attribute__((ext_vector_type(4)));

__device__ __forceinline__ float sigmoidf_(float x) { return 1.f / (1.f + expf(-x)); }

__device__ __forceinline__ unsigned short bf16_rne(float f) {
    uint32_t u = __builtin_bit_cast(uint32_t, f);
    u += 0x7FFFu + ((u >> 16) & 1u);
    return (unsigned short)(u >> 16);
}
__device__ __forceinline__ float bf16_tof(unsigned short h) {
    uint32_t u = ((uint32_t)h) << 16;
    return __builtin_bit_cast(float, u);
}

// ---------------------------------------------------------------------------
// Weight split: conv1/conv2 -> 3-way bf16 split, conv4 -> 2-way, conv3 -> bf16
// ---------------------------------------------------------------------------
__global__ __launch_bounds__(256) void wsplit_kernel(
    const float* __restrict__ w1, const float* __restrict__ w2,
    const float* __restrict__ w3, const float* __restrict__ w4,
    unsigned short* __restrict__ w1h, unsigned short* __restrict__ w1m, unsigned short* __restrict__ w1l,
    unsigned short* __restrict__ w2h, unsigned short* __restrict__ w2m, unsigned short* __restrict__ w2l,
    unsigned short* __restrict__ w4h, unsigned short* __restrict__ w4l,
    unsigned short* __restrict__ w3b) {
    const int i = blockIdx.x * 256 + threadIdx.x;  // 65536 weights each
    {
        float x = w1[i];
        unsigned short h = bf16_rne(x); float r = x - bf16_tof(h);
        unsigned short m = bf16_rne(r); float r2 = r - bf16_tof(m);
        w1h[i] = h; w1m[i] = m; w1l[i] = bf16_rne(r2);
    }
    {
        float x = w2[i];
        unsigned short h = bf16_rne(x); float r = x - bf16_tof(h);
        unsigned short m = bf16_rne(r); float r2 = r - bf16_tof(m);
        w2h[i] = h; w2m[i] = m; w2l[i] = bf16_rne(r2);
    }
    {
        float x = w4[i];
        unsigned short h = bf16_rne(x); float r = x - bf16_tof(h);
        w4h[i] = h; w4l[i] = bf16_rne(r);
    }
    w3b[i] = bf16_rne(w3[i]);
}

// ---------------------------------------------------------------------------
// Transpose + split: X fp32 [n][C][HW] -> NS bf16 arrays [n][HW][C]
// grid (HW/64, C/64, N), 256 threads
// ---------------------------------------------------------------------------
template <int NS>
__global__ __launch_bounds__(256) void tsplit_kernel(const float* __restrict__ X,
                                                     unsigned short* __restrict__ O0,
                                                     unsigned short* __restrict__ O1,
                                                     unsigned short* __restrict__ O2) {
    const int hw0 = blockIdx.x * 64, c0 = blockIdx.y * 64, n = blockIdx.z;
    __shared__ float sT[64][65];
    const int tid = threadIdx.x;
    {
        const int hwl = (tid & 15) << 2;
        const int cl = tid >> 4;  // 0..15
#pragma unroll
        for (int p = 0; p < 4; ++p) {
            const int c = cl + p * 16;
            const float4 v = *(const float4*)(X + ((size_t)(n * CC + c0 + c)) * HW + hw0 + hwl);
            sT[c][hwl] = v.x; sT[c][hwl + 1] = v.y; sT[c][hwl + 2] = v.z; sT[c][hwl + 3] = v.w;
        }
    }
    __syncthreads();
    const int hwl = tid >> 2, cb = (tid & 3) << 4;
    unsigned short h[16], m[16], l[16];
#pragma unroll
    for (int j = 0; j < 16; ++j) {
        const float x = sT[cb + j][hwl];
        const unsigned short hh = bf16_rne(x);
        h[j] = hh;
        if (NS >= 2) {
            const float r = x - bf16_tof(hh);
            const unsigned short mm = bf16_rne(r);
            m[j] = mm;
            if (NS >= 3) l[j] = bf16_rne(r - bf16_tof(mm));
        }
    }
    const size_t ob = ((size_t)(n * HW + hw0 + hwl)) * 256 + c0 + cb;
    *(int4*)(O0 + ob) = *(int4*)&h[0]; *(int4*)(O0 + ob + 8) = *(int4*)&h[8];
    if (NS >= 2) { *(int4*)(O1 + ob) = *(int4*)&m[0]; *(int4*)(O1 + ob + 8) = *(int4*)&m[8]; }
    if (NS >= 3) { *(int4*)(O2 + ob) = *(int4*)&l[0]; *(int4*)(O2 + ob + 8) = *(int4*)&l[8]; }
}

// ---------------------------------------------------------------------------
// MFMA GEMM core v2: Y-tile 128(o) x 64(hw), K=256 in steps of 32, 4 waves.
// Each wave owns 32 o-rows (2 o-fragments) x 64 hw -> B-fragment reads are
// amortized over 2x MFMAs vs the 64-o version.
// acc[f][nt]: o = o0 + f*64 + wv*16 + quad*4 + reg, hw = hw0 + nt*16 + (lane&15)
// ---------------------------------------------------------------------------
template <int NS>
__device__ __forceinline__ void mfma_core2(const unsigned short* X0,
                                           const unsigned short* X1,
                                           const unsigned short* X2,
                                           const unsigned short* W0,
                                           const unsigned short* W1,
                                           const unsigned short* W2,
                                           int n, int hw0, int o0, f32x4 (&acc)[2][4]) {
    __shared__ unsigned short sX[NS][64][40];   // pitch 40 us = 80 B
    __shared__ unsigned short sW[NS][128][40];
    const int tid = threadIdx.x;
    const int lane = tid & 63, wv = tid >> 6, quad = lane >> 4, nlo = lane & 15;
    const int srow = tid >> 2, skoff = (tid & 3) << 3;
    const unsigned short* Xs[3] = {X0, X1, X2};
    const unsigned short* Ws[3] = {W0, W1, W2};
    const size_t xg = ((size_t)(n * HW + hw0 + srow)) * 256 + skoff;
    const size_t wg = ((size_t)(o0 + srow)) * 256 + skoff;
    for (int k0 = 0; k0 < 256; k0 += 32) {
#pragma unroll
        for (int s = 0; s < NS; ++s) {
            *(int4*)&sX[s][srow][skoff] = *(const int4*)(Xs[s] + xg + k0);
            *(int4*)&sW[s][srow][skoff] = *(const int4*)(Ws[s] + wg + k0);
            *(int4*)&sW[s][64 + srow][skoff] = *(const int4*)(Ws[s] + wg + 64 * 256 + k0);
        }
        __syncthreads();
        bf16x8 af[NS][2];
#pragma unroll
        for (int s = 0; s < NS; ++s) {
            af[s][0] = *(const bf16x8*)&sW[s][wv * 16 + nlo][quad * 8];
            af[s][1] = *(const bf16x8*)&sW[s][64 + wv * 16 + nlo][quad * 8];
        }
#pragma unroll
        for (int nt = 0; nt < 4; ++nt) {
            bf16x8 bfr[NS];
#pragma unroll
            for (int s = 0; s < NS; ++s) bfr[s] = *(const bf16x8*)&sX[s][nt * 16 + nlo][quad * 8];
#pragma unroll
            for (int f = 0; f < 2; ++f) {
                // accumulate smallest-magnitude products first
                if (NS == 3) {
                    acc[f][nt] = __builtin_amdgcn_mfma_f32_16x16x32_bf16(af[1][f], bfr[1], acc[f][nt], 0, 0, 0);
                    acc[f][nt] = __builtin_amdgcn_mfma_f32_16x16x32_bf16(af[0][f], bfr[2], acc[f][nt], 0, 0, 0);
                    acc[f][nt] = __builtin_amdgcn_mfma_f32_16x16x32_bf16(af[2][f], bfr[0], acc[f][nt], 0, 0, 0);
                    acc[f][nt] = __builtin_amdgcn_mfma_f32_16x16x32_bf16(af[0][f], bfr[1], acc[f][nt], 0, 0, 0);
                    acc[f][nt] = __builtin_amdgcn_mfma_f32_16x16x32_bf16(af[1][f], bfr[0], acc[f][nt], 0, 0, 0);
                    acc[f][nt] = __builtin_amdgcn_mfma_f32_16x16x32_bf16(af[0][f], bfr[0], acc[f][nt], 0, 0, 0);
                } else if (NS == 2) {
                    acc[f][nt] = __builtin_amdgcn_mfma_f32_16x16x32_bf16(af[0][f], bfr[1], acc[f][nt], 0, 0, 0);
                    acc[f][nt] = __builtin_amdgcn_mfma_f32_16x16x32_bf16(af[1][f], bfr[0], acc[f][nt], 0, 0, 0);
                    acc[f][nt] = __builtin_amdgcn_mfma_f32_16x16x32_bf16(af[0][f], bfr[0], acc[f][nt], 0, 0, 0);
                } else {
                    acc[f][nt] = __builtin_amdgcn_mfma_f32_16x16x32_bf16(af[0][f], bfr[0], acc[f][nt], 0, 0, 0);
                }
            }
        }
        __syncthreads();
    }
}

// grid (HW/64, CC/128, N)
template <int NS>
__global__ __launch_bounds__(256, 3) void gemm_mfma_kernel(
    const unsigned short* __restrict__ X0, const unsigned short* __restrict__ X1,
    const unsigned short* __restrict__ X2, const unsigned short* __restrict__ W0,
    const unsigned short* __restrict__ W1, const unsigned short* __restrict__ W2,
    const float* __restrict__ bias, float* __restrict__ Y) {
    const int hw0 = blockIdx.x * 64, o0 = blockIdx.y * 128, n = blockIdx.z;
    f32x4 acc[2][4] = {};
    mfma_core2<NS>(X0, X1, X2, W0, W1, W2, n, hw0, o0, acc);
    const int lane = threadIdx.x & 63, wv = threadIdx.x >> 6;
    const int quad = lane >> 4, nlo = lane & 15;
#pragma unroll
    for (int f = 0; f < 2; ++f) {
        const int om = o0 + f * 64 + wv * 16 + quad * 4;
#pragma unroll
        for (int nt = 0; nt < 4; ++nt) {
            const int hw = hw0 + nt * 16 + nlo;
#pragma unroll
            for (int r = 0; r < 4; ++r) {
                const int o = om + r;
                Y[((size_t)(n * CC + o)) * HW + hw] = acc[f][nt][r] + bias[o];
            }
        }
    }
}

// conv3 GEMM (plain bf16) with fused final-combine epilogue:
// xL = (conv3(dw)+b3)*gate[n,o] + A + (s_pix*XG - mu_g)*isd_g*gamma[o] + beta[o] + XG*ca_sig[n,o]
__global__ __launch_bounds__(256, 3) void gemm_final_kernel(
    const unsigned short* __restrict__ X0, const unsigned short* __restrict__ W0,
    const float* __restrict__ bias,
    const float* __restrict__ A, const float* __restrict__ XG, const float* __restrict__ s_pix,
    const float* __restrict__ gate, const float* __restrict__ ca_sig,
    const float* __restrict__ mu_g, const float* __restrict__ isd_g,
    const float* __restrict__ gamma, const float* __restrict__ beta,
    float* __restrict__ out) {
    const int hw0 = blockIdx.x * 64, o0 = blockIdx.y * 128, n = blockIdx.z;
    f32x4 acc[2][4] = {};
    mfma_core2<1>(X0, nullptr, nullptr, W0, nullptr, nullptr, n, hw0, o0, acc);
    const int lane = threadIdx.x & 63, wv = threadIdx.x >> 6;
    const int quad = lane >> 4, nlo = lane & 15;
#pragma unroll
    for (int f = 0; f < 2; ++f) {
        const int om = o0 + f * 64 + wv * 16 + quad * 4;
#pragma unroll
        for (int nt = 0; nt < 4; ++nt) {
            const int hw = hw0 + nt * 16 + nlo;
            const int pix = n * HW + hw;
            const float sp = s_pix[pix];
#pragma unroll
            for (int r = 0; r < 4; ++r) {
                const int o = om + r;
                const float g = gate[n * CC + o];
                const float cs = ca_sig[n * CC + o];
                const float mu = mu_g[n * 16 + (o >> 4)];
                const float isd = isd_g[n * 16 + (o >> 4)];
                const size_t rowi = ((size_t)(n * CC + o)) * HW + hw;
                const float xg = XG[rowi];
                const float gui = (sp * xg - mu) * isd * gamma[o] + beta[o];
                out[rowi] = (acc[f][nt][r] + bias[o]) * g + A[rowi] + gui + xg * cs;
            }
        }
    }
}

// grid NC (4096): XG = g1+g2, per-(n,c) sum and sumsq
__global__ __launch_bounds__(256) void xg_stats_kernel(const float* __restrict__ g1,
                                                       const float* __restrict__ g2,
                                                       float* __restrict__ XG,
                                                       float* __restrict__ sum_c,
                                                       float* __restrict__ sq_c) {
    const size_t base = (size_t)blockIdx.x * HW;
    float s = 0.f, q = 0.f;
#pragma unroll 4
    for (int r = 0; r < 16; ++r) {
        const size_t i = base + threadIdx.x + r * 256;
        const float xg = g1[i] + g2[i];
        XG[i] = xg;
        s += xg;
        q += xg * xg;
    }
    __shared__ float sm[8];
    for (int off = 32; off; off >>= 1) { s += __shfl_down(s, off); q += __shfl_down(q, off); }
    const int w = threadIdx.x >> 6;
    if ((threadIdx.x & 63) == 0) { sm[w] = s; sm[4 + w] = q; }
    __syncthreads();
    if (threadIdx.x == 0) {
        sum_c[blockIdx.x] = sm[0] + sm[1] + sm[2] + sm[3];
        sq_c[blockIdx.x] = sm[4] + sm[5] + sm[6] + sm[7];
    }
}

// grid N (16): rw=sigmoid(mean), ca conv1d(k=5,pad2)+sigmoid, group mu / 1/(sd+1e-10)
// Also zeroes xlow_sum for the downstream atomic accumulation.
__global__ __launch_bounds__(256) void stats2_kernel(const float* __restrict__ sum_c,
                                                     const float* __restrict__ sq_c,
                                                     const float* __restrict__ caw,
                                                     float* __restrict__ rw,
                                                     float* __restrict__ ca_sig,
                                                     float* __restrict__ mu_g,
                                                     float* __restrict__ isd_g,
                                                     float* __restrict__ xlow_sum) {
    const int n = blockIdx.x, c = threadIdx.x;
    __shared__ float m[256];
    const float mean = sum_c[n * CC + c] * (1.f / (float)HW);
    m[c] = mean;
    rw[n * CC + c] = sigmoidf_(mean);
    xlow_sum[n * CC + c] = 0.f;
    __syncthreads();
    float y = 0.f;
#pragma unroll
    for (int k = 0; k < 5; ++k) {
        const int cc = c - 2 + k;
        if (cc >= 0 && cc < 256) y += m[cc] * caw[k];
    }
    ca_sig[n * CC + c] = sigmoidf_(y);
    if (c < 16) {
        float S = 0.f, Q = 0.f;
        for (int j = 0; j < 16; ++j) {
            S += sum_c[n * CC + c * 16 + j];
            Q += sq_c[n * CC + c * 16 + j];
        }
        const float cnt = 65536.f;
        const float mu = S / cnt;
        float var = (Q - S * S / cnt) * (1.f / (cnt - 1.f));
        var = fmaxf(var, 0.f);
        mu_g[n * 16 + c] = mu;
        isd_g[n * 16 + c] = 1.f / (sqrtf(var) + 1e-10f);
    }
}

// grid N*HW/256 (256): s_pix = sigmoid(conv4g(XG))
__global__ __launch_bounds__(256) void conv4g_kernel(const float* __restrict__ XG,
                                                     const float* __restrict__ cgw,
                                                     const float* __restrict__ cgb,
                                                     float* __restrict__ s_pix) {
    __shared__ float w[256];
    w[threadIdx.x] = cgw[threadIdx.x];
    __syncthreads();
    const int p = blockIdx.x * 256 + threadIdx.x;
    const int n = p >> 12, hw = p & 4095;
    const float* base = XG + (size_t)n * CC * HW + hw;
    float s = cgb[0];
#pragma unroll 8
    for (int c = 0; c < 256; ++c) s += base[(size_t)c * HW] * w[c];
    s_pix[p] = sigmoidf_(s);
}

// ---------------------------------------------------------------------------
// Fused masks + conv4-input transpose/split. grid (HW/64, CC/64, N):
//  - reads g1, g2, XG tiles; computes w1/w2 vs rw -> cu
//  - x_low = XG*(2-cu) -> in-place over g1; atomicAdd per-(n,c) row sums
//  - x_up  = XG*cu -> 2-way bf16 split, transposed [n][HW][C] -> O0/O1
// ---------------------------------------------------------------------------
__global__ __launch_bounds__(256) void masks_split_kernel(
    float* g1_xlow,  // aliased in/out
    const float* __restrict__ g2,
    const float* __restrict__ XG,
    const float* __restrict__ rw,
    const float* __restrict__ bng, const float* __restrict__ bnb,
    const float* __restrict__ bnrm, const float* __restrict__ bnrv,
    unsigned short* __restrict__ O0, unsigned short* __restrict__ O1,
    float* __restrict__ xlow_sum) {
    const int hw0 = blockIdx.x * 64, c0 = blockIdx.y * 64, n = blockIdx.z;
    __shared__ float sT[64][65];
    const int tid = threadIdx.x;
    const int cl = tid >> 2;        // 0..63 (c-row within tile)
    const int q = tid & 3;          // lane-in-row
    const int c = c0 + cl;
    const float inv = bng[c] / sqrtf(bnrv[c] + 1e-5f);
    const float off = bnb[c] - bnrm[c] * inv;
    const float rwv = rw[n * CC + c];
    const size_t rowb = ((size_t)(n * CC + c)) * HW + hw0;
    float lsum = 0.f;
#pragma unroll
    for (int j = 0; j < 4; ++j) {
        const int hwl = q * 4 + j * 16;
        const float4 a = *(const float4*)(g1_xlow + rowb + hwl);
        const float4 b = *(const float4*)(g2 + rowb + hwl);
        const float4 x = *(const float4*)(XG + rowb + hwl);
        const float* ap = &a.x; const float* bp = &b.x; const float* xp = &x.x;
        float4 xlv;
        float* xlp = &xlv.x;
#pragma unroll
        for (int e = 0; e < 4; ++e) {
            const float w1 = sigmoidf_(inv * ap[e] + off);
            const float w2 = sigmoidf_(inv * bp[e] + off);
            const float cu = (rwv >= w1 ? 1.f : 0.f) + (rwv >= w2 ? 1.f : 0.f);
            const float xu = xp[e] * cu;
            const float xl = xp[e] * (2.f - cu);
            sT[cl][hwl + e] = xu;
            xlp[e] = xl;
            lsum += xl;
        }
        *(float4*)(g1_xlow + rowb + hwl) = xlv;
    }
    lsum += __shfl_xor(lsum, 1);
    lsum += __shfl_xor(lsum, 2);
    if (q == 0) atomicAdd(&xlow_sum[n * CC + c], lsum);
    __syncthreads();
    // phase 2: transposed 2-way split store (same pattern as tsplit<2>)
    const int hwl2 = tid >> 2, cb = (tid & 3) << 4;
    unsigned short h[16], m[16];
#pragma unroll
    for (int j = 0; j < 16; ++j) {
        const float x = sT[cb + j][hwl2];
        const unsigned short hh = bf16_rne(x);
        h[j] = hh;
        m[j] = bf16_rne(x - bf16_tof(hh));
    }
    const size_t ob = ((size_t)(n * HW + hw0 + hwl2)) * 256 + c0 + cb;
    *(int4*)(O0 + ob) = *(int4*)&h[0]; *(int4*)(O0 + ob + 8) = *(int4*)&h[8];
    *(int4*)(O1 + ob) = *(int4*)&m[0]; *(int4*)(O1 + ob + 8) = *(int4*)&m[8];
}

// grid N: gate = softmax_c(relu(xlow_mean @ gate_w^T + gate_b))
__global__ __launch_bounds__(256) void gate_kernel(const float* __restrict__ xlow_sum,
                                                   const float* __restrict__ gatew,
                                                   const float* __restrict__ gateb,
                                                   float* __restrict__ gate) {
    const int n = blockIdx.x, c = threadIdx.x;
    __shared__ float xm[256];
    __shared__ float red[256];
    xm[c] = xlow_sum[n * CC + c] * (1.f / (float)HW);
    __syncthreads();
    float acc = gateb[c];
    const float* wr = gatew + (size_t)c * 256;
#pragma unroll 8
    for (int k = 0; k < 256; ++k) acc += xm[k] * wr[k];
    const float v = fmaxf(acc, 0.f);
    red[c] = v;
    __syncthreads();
    for (int s = 128; s > 0; s >>= 1) {
        if (c < s) red[c] = fmaxf(red[c], red[c + s]);
        __syncthreads();
    }
    const float mx = red[0];
    __syncthreads();
    const float e = expf(v - mx);
    red[c] = e;
    __syncthreads();
    for (int s = 128; s > 0; s >>= 1) {
        if (c < s) red[c] += red[c + s];
        __syncthreads();
    }
    gate[n * CC + c] = e / red[0];
}

// grid NC: depthwise 3x3 (pad 1) on x_low via LDS slab
__global__ __launch_bounds__(256) void dwconv_kernel(const float* __restrict__ xlow,
                                                     const float* __restrict__ dww,
                                                     const float* __restrict__ dwb,
                                                     float* __restrict__ out) {
    const int c = blockIdx.x & 255;
    __shared__ float sl[64][65];
    const size_t base = (size_t)blockIdx.x * HW;
    for (int r = 0; r < 16; ++r) {
        const int idx = threadIdx.x + r * 256;
        sl[idx >> 6][idx & 63] = xlow[base + idx];
    }
    float wk[9];
#pragma unroll
    for (int j = 0; j < 9; ++j) wk[j] = dww[c * 9 + j];
    const float bias = dwb[c];
    __syncthreads();
    for (int r = 0; r < 16; ++r) {
        const int idx = threadIdx.x + r * 256;
        const int h = idx >> 6, w = idx & 63;
        float acc = bias;
#pragma unroll
        for (int dh = 0; dh < 3; ++dh) {
            const int hh = h + dh - 1;
            if (hh < 0 || hh > 63) continue;
#pragma unroll
            for (int dw2 = 0; dw2 < 3; ++dw2) {
                const int ww2 = w + dw2 - 1;
                if (ww2 < 0 || ww2 > 63) continue;
                acc += sl[hh][ww2] * wk[dh * 3 + dw2];
            }
        }
        out[base + idx] = acc;
    }
}

// grid NC: xh[n,c,h]=mean_w xL, xw[n,c,w]=mean_h xL
__global__ __launch_bounds__(256) void pool_kernel(const float* __restrict__ xL,
                                                   float* __restrict__ xh,
                                                   float* __restrict__ xw) {
    __shared__ float sl[64][65];
    const size_t base = (size_t)blockIdx.x * HW;
    for (int r = 0; r < 16; ++r) {
        const int idx = threadIdx.x + r * 256;
        sl[idx >> 6][idx & 63] = xL[base + idx];
    }
    __syncthreads();
    const int t = threadIdx.x;
    if (t < 64) {
        float s = 0.f;
        for (int w = 0; w < 64; ++w) s += sl[t][w];
        xh[(size_t)blockIdx.x * 64 + t] = s * (1.f / 64.f);
    } else if (t < 128) {
        const int w = t - 64;
        float s = 0.f;
        for (int h = 0; h < 64; ++h) s += sl[h][w];
        xw[(size_t)blockIdx.x * 64 + w] = s * (1.f / 64.f);
    }
}

// grid N: yc = relu(bn(la1 @ [xh;xw])); sh = sig(fh@yc_h), sw = sig(fw@yc_w)
__global__ __launch_bounds__(256) void local_att_kernel(const float* __restrict__ xh,
                                                        const float* __restrict__ xw,
                                                        const float* __restrict__ la1w,
                                                        const float* __restrict__ lag,
                                                        const float* __restrict__ lab,
                                                        const float* __restrict__ larm,
                                                        const float* __restrict__ larv,
                                                        const float* __restrict__ fhw,
                                                        const float* __restrict__ fww,
                                                        float* __restrict__ sh,
                                                        float* __restrict__ sw) {
    const int n = blockIdx.x;
    __shared__ float w1s[16 * 256];
    __shared__ float fhs[256 * 16];
    __shared__ float fws[256 * 16];
    __shared__ float ycs[16][128];
    for (int i = threadIdx.x; i < 4096; i += 256) {
        w1s[i] = la1w[i];
        fhs[i] = fhw[i];
        fws[i] = fww[i];
    }
    __syncthreads();
    for (int idx = threadIdx.x; idx < 2048; idx += 256) {
        const int m = idx >> 7, p = idx & 127;
        const float* vsrc = (p < 64) ? (xh + (size_t)n * CC * 64 + p)
                                     : (xw + (size_t)n * CC * 64 + (p - 64));
        float acc = 0.f;
#pragma unroll 8
        for (int c = 0; c < 256; ++c) acc += w1s[m * 256 + c] * vsrc[(size_t)c * 64];
        const float inv = lag[m] / sqrtf(larv[m] + 1e-5f);
        const float off = lab[m] - larm[m] * inv;
        ycs[m][p] = fmaxf(inv * acc + off, 0.f);
    }
    __syncthreads();
    for (int idx = threadIdx.x; idx < 16384; idx += 256) {
        const int c = idx >> 6, h = idx & 63;
        float a1 = 0.f, a2 = 0.f;
#pragma unroll
        for (int m = 0; m < 16; ++m) {
            a1 += fhs[c * 16 + m] * ycs[m][h];
            a2 += fws[c * 16 + m] * ycs[m][64 + h];
        }
        sh[(size_t)n * CC * 64 + idx] = sigmoidf_(a1);
        sw[(size_t)n * CC * 64 + idx] = sigmoidf_(a2);
    }
}

// grid NC: out *= sh[h]*sw[w], in place
__global__ __launch_bounds__(256) void final_kernel(float* __restrict__ out,
                                                    const float* __restrict__ sh,
                                                    const float* __restrict__ sw) {
    __shared__ float shs[64], sws[64];
    const int t = threadIdx.x;
    if (t < 64) shs[t] = sh[(size_t)blockIdx.x * 64 + t];
    else if (t < 128) sws[t - 64] = sw[(size_t)blockIdx.x * 64 + (t - 64)];
    __syncthreads();
    const size_t base = (size_t)blockIdx.x * HW;
#pragma unroll 4
    for (int r = 0; r < 16; ++r) {
        const int idx = t + r * 256;
        out[base + idx] *= shs[idx >> 6] * sws[idx & 63];
    }
}

extern "C" void kernel_launch(void* const* d_in, const int* in_sizes, int n_in,
                              void* d_out, int out_size, void* d_ws, size_t ws_size,
                              hipStream_t stream) {
    const float* x1 = (const float*)d_in[0];
    const float* x2 = (const float*)d_in[1];
    const float* c1w = (const float*)d_in[2];
    const float* c1b = (const float*)d_in[3];
    const float* c2w = (const float*)d_in[4];
    const float* c2b = (const float*)d_in[5];
    const float* c3w = (const float*)d_in[6];
    const float* c3b = (const float*)d_in[7];
    const float* c4w = (const float*)d_in[8];
    const float* c4b = (const float*)d_in[9];
    const float* cgw = (const float*)d_in[10];
    const float* cgb = (const float*)d_in[11];
    const float* bng = (const float*)d_in[12];
    const float* bnb = (const float*)d_in[13];
    const float* bnrm = (const float*)d_in[14];
    const float* bnrv = (const float*)d_in[15];
    const float* gamma = (const float*)d_in[16];
    const float* beta = (const float*)d_in[17];
    const float* gatew = (const float*)d_in[18];
    const float* gateb = (const float*)d_in[19];
    const float* dww = (const float*)d_in[20];
    const float* dwb = (const float*)d_in[21];
    // d_in[22], d_in[23]: interact_w/b — dead code (softmax over size-1 axis == 1)
    const float* caw = (const float*)d_in[24];
    const float* la1w = (const float*)d_in[25];
    const float* lag = (const float*)d_in[26];
    const float* lab = (const float*)d_in[27];
    const float* larm = (const float*)d_in[28];
    const float* larv = (const float*)d_in[29];
    const float* fhw = (const float*)d_in[30];
    const float* fww = (const float*)d_in[31];

    // ---- Workspace plan (R4's proven footprint) ----
    // buf0: g1 -> x_low -> [conv3 split (1 FSZ us)]
    // buf1: [conv1 splits hi,mid] -> g2 -> dw -> A (conv4 out)
    // buf2: [conv1/conv2 lo split] -> XG
    // d_out: [conv2 splits hi,mid] -> [x_up splits hi,lo] -> final out
    float* ws = (float*)d_ws;
    float* buf0 = ws;
    float* buf1 = ws + FSZ;
    float* buf2 = ws + 2 * FSZ;
    float* sp = ws + 3 * FSZ;
    float* sum_c = sp;    sp += 4096;   // later reused as gate
    float* sq_c = sp;     sp += 4096;
    float* rw = sp;       sp += 4096;
    float* ca_sig = sp;   sp += 4096;
    float* xlow_sum = sp; sp += 4096;
    float* mu_g = sp;     sp += 256;
    float* isd_g = sp;    sp += 256;
    float* s_pix = sp;    sp += (size_t)NN * HW;       // 65536
    float* xh = sp;       sp += (size_t)NN * CC * 64;  // 262144
    float* xwb = sp;      sp += (size_t)NN * CC * 64;
    float* shb = sp;      sp += (size_t)NN * CC * 64;
    float* swb = sp;      sp += (size_t)NN * CC * 64;
    // weight splits overlap shb/swb (written only at step 12; weights dead by then)
    unsigned short* wsp = (unsigned short*)shb;
    unsigned short* w1h = wsp + 0 * 65536;
    unsigned short* w1m = wsp + 1 * 65536;
    unsigned short* w1l = wsp + 2 * 65536;
    unsigned short* w2h = wsp + 3 * 65536;
    unsigned short* w2m = wsp + 4 * 65536;
    unsigned short* w2l = wsp + 5 * 65536;
    unsigned short* w4h = wsp + 6 * 65536;
    unsigned short* w4l = wsp + 7 * 65536;
    unsigned short* w3b = wsp + 8 * 65536;

    float* out = (float*)d_out;

    const dim3 gt(HW / 64, CC / 64, NN);   // tsplit/masks grids (64, 4, 16)
    const dim3 gg(HW / 64, CC / 128, NN);  // gemm grids (64, 2, 16)

    // 0: weight splits
    wsplit_kernel<<<256, 256, 0, stream>>>(c1w, c2w, c3w, c4w, w1h, w1m, w1l,
                                           w2h, w2m, w2l, w4h, w4l, w3b);
    // 1: g1 = conv1(x1)  (3-split ~fp32 MFMA). Splits: buf1 (hi,mid) + buf2 (lo).
    {
        unsigned short* sx0 = (unsigned short*)buf1;
        unsigned short* sx1 = (unsigned short*)buf1 + FSZ;
        unsigned short* sx2 = (unsigned short*)buf2;
        tsplit_kernel<3><<<gt, 256, 0, stream>>>(x1, sx0, sx1, sx2);
        gemm_mfma_kernel<3><<<gg, 256, 0, stream>>>(sx0, sx1, sx2, w1h, w1m, w1l, c1b, buf0);
    }
    // 2: g2 = conv2(x2). Splits: d_out (hi,mid) + buf2 (lo). g2 -> buf1.
    {
        unsigned short* sx0 = (unsigned short*)out;
        unsigned short* sx1 = (unsigned short*)out + FSZ;
        unsigned short* sx2 = (unsigned short*)buf2;
        tsplit_kernel<3><<<gt, 256, 0, stream>>>(x2, sx0, sx1, sx2);
        gemm_mfma_kernel<3><<<gg, 256, 0, stream>>>(sx0, sx1, sx2, w2h, w2m, w2l, c2b, buf1);
    }
    // 3: XG = g1+g2 -> buf2 + per-channel stats
    xg_stats_kernel<<<NN * CC, 256, 0, stream>>>(buf0, buf1, buf2, sum_c, sq_c);
    // 4: rw, channel-att sigmoid, group mu/invsd (+ zero xlow_sum)
    stats2_kernel<<<NN, 256, 0, stream>>>(sum_c, sq_c, caw, rw, ca_sig, mu_g, isd_g, xlow_sum);
    // 5: s_pix = sigmoid(conv4g(XG))
    conv4g_kernel<<<NN * HW / 256, 256, 0, stream>>>(buf2, cgw, cgb, s_pix);
    // 6: fused masks + conv4-input split: x_low -> buf0 (in place), x_up splits -> d_out,
    //    xlow_sum via atomics (zeroed in step 4)
    {
        unsigned short* ux0 = (unsigned short*)out;
        unsigned short* ux1 = (unsigned short*)out + FSZ;
        masks_split_kernel<<<gt, 256, 0, stream>>>(buf0, buf1, buf2, rw, bng, bnb, bnrm, bnrv,
                                                   ux0, ux1, xlow_sum);
    }
    // 7: gate softmax (output reuses sum_c)
    float* gate = sum_c;
    gate_kernel<<<NN, 256, 0, stream>>>(xlow_sum, gatew, gateb, gate);
    // 8: dwconv on x_low -> buf1 (g2 dead)
    dwconv_kernel<<<NN * CC, 256, 0, stream>>>(buf0, dww, dwb, buf1);
    // 9: conv3 input split: dw(buf1) -> buf0 ushorts (x_low dead)
    {
        unsigned short* sx0 = (unsigned short*)buf0;
        tsplit_kernel<1><<<gt, 256, 0, stream>>>(buf1, sx0, nullptr, nullptr);
    }
    // 10: A = conv4(x_up) (2-split MFMA): d_out splits -> buf1 (dw dead after step 9)
    {
        unsigned short* ux0 = (unsigned short*)out;
        unsigned short* ux1 = (unsigned short*)out + FSZ;
        gemm_mfma_kernel<2><<<gg, 256, 0, stream>>>(ux0, ux1, nullptr, w4h, w4l, nullptr,
                                                    c4b, buf1);
    }
    // 11: xL = conv3(dw)*gate + A + x_gui + temp -> d_out (x_up splits dead)
    {
        unsigned short* sx0 = (unsigned short*)buf0;
        gemm_final_kernel<<<gg, 256, 0, stream>>>(sx0, w3b, c3b, buf1, buf2, s_pix,
                                                  gate, ca_sig, mu_g, isd_g, gamma, beta, out);
    }
    // 12: pools
    pool_kernel<<<NN * CC, 256, 0, stream>>>(out, xh, xwb);
    // 13: coordinate attention -> sh, sw (overwrites weight-split region — weights dead)
    local_att_kernel<<<NN, 256, 0, stream>>>(xh, xwb, la1w, lag, lab, larm, larv,
                                             fhw, fww, shb, swb);
    // 14: out *= sh*sw
    final_kernel<<<NN * CC, 256, 0, stream>>>(out, shb, swb);
}